// Round 1
// baseline (202.146 us; speedup 1.0000x reference)
//
#include <hip/hip_runtime.h>
#include <hip/hip_bf16.h>

// MHA forward: B=2, S=2048, D=1024, H=16, depth=64.
// All GEMMs in bf16 MFMA (16x16x32), fp32 accumulation. Threshold is 2% of
// ref absmax -> bf16 has ~10x margin.

typedef __bf16 bf16x8 __attribute__((ext_vector_type(8)));
typedef float f32x4 __attribute__((ext_vector_type(4)));
typedef unsigned short u16;
typedef unsigned short u16x4 __attribute__((ext_vector_type(4)));
typedef unsigned short u16x8 __attribute__((ext_vector_type(8)));
typedef float f32x4v __attribute__((ext_vector_type(4))) ;

__device__ __forceinline__ u16 f2bf(float f) {
  union { float f; unsigned u; } x; x.f = f;
  return (u16)((x.u + 0x7fffu + ((x.u >> 16) & 1u)) >> 16);   // RNE
}

// async global->LDS, 16B per lane. LDS dest is wave-uniform base (+lane*16 in HW).
__device__ __forceinline__ void load_lds16(const void* g, void* l) {
  __builtin_amdgcn_global_load_lds((const __attribute__((address_space(1))) void*)g,
                                   (__attribute__((address_space(3))) void*)l,
                                   16, 0, 0);
}

// LDS tile readers. Rows XOR-swizzled with ((row&7)<<4) to kill the
// 16-way bank conflict of 128B/256B-stride row-major reads (G4).
__device__ __forceinline__ bf16x8 frag128(const u16* base, int row, int ch) {
  return *(const bf16x8*)((const char*)base + row * 128 + (((ch) ^ (row & 7)) << 4));
}
__device__ __forceinline__ bf16x8 frag256(const u16* base, int row, int ch) {
  return *(const bf16x8*)((const char*)base + row * 256 + (((ch) ^ (row & 7)) << 4));
}

// ---------------------------------------------------------------- convert
__global__ __launch_bounds__(256) void cvt_f32_to_bf16(
    const float* __restrict__ src, u16* __restrict__ dst, int n4) {
  int i = blockIdx.x * 256 + threadIdx.x;
  if (i >= n4) return;
  f32x4 v = ((const f32x4*)src)[i];
  u16x4 o;
#pragma unroll
  for (int j = 0; j < 4; ++j) o[j] = f2bf(v[j]);
  ((u16x4*)dst)[i] = o;
}

// ---------------------------------------------------------------- GEMM
// C[M,N] = A[M,K] @ Bw[N,K]^T (+bias). BMxBN=BMx128 tile, 4 waves (2x2),
// wave tile (BM/2)x64. MODE 0: QKV epilogue -> bf16 [b,h,s,64] (Q scaled 1/8).
// MODE 1: fp32 out + bias.
template <int BM, int MODE>
__global__ __launch_bounds__(256) void gemm_bf16(
    const u16* __restrict__ A, const u16* __restrict__ Bw,
    const float* __restrict__ bias0, const float* __restrict__ bias1,
    const float* __restrict__ bias2,
    u16* __restrict__ o_q, u16* __restrict__ o_k, u16* __restrict__ o_v,
    float* __restrict__ o_f, int K) {
  constexpr int MBF = BM / 32;           // M-frags per wave
  __shared__ u16 sA[BM * 64];
  __shared__ u16 sB[128 * 64];
  const int tid = threadIdx.x, l = tid & 63, w = tid >> 6;
  const int wr = w >> 1, wc = w & 1;
  const int lr = l & 15, lq = l >> 4;
  const int m0 = blockIdx.y * BM, n0 = blockIdx.x * 128;

  f32x4 acc[MBF][4];
#pragma unroll
  for (int mb = 0; mb < MBF; ++mb)
#pragma unroll
    for (int nb = 0; nb < 4; ++nb) acc[mb][nb] = f32x4{0.f, 0.f, 0.f, 0.f};

  const int nkt = K / 64;
  for (int kt = 0; kt < nkt; ++kt) {
    // stage A (BM/32 calls) and B (4 calls); source pre-swizzled so linear
    // LDS dest ends up XOR-swizzled (rule #21: both-sides-or-neither).
#pragma unroll
    for (int i = 0; i < BM / 32; ++i) {
      int p = (i * 4 + w) * 1024 + l * 16;
      int row = p >> 7, ch = ((p >> 4) & 7) ^ (row & 7);
      load_lds16(A + (size_t)(m0 + row) * K + kt * 64 + ch * 8,
                 (char*)sA + (i * 4 + w) * 1024);
    }
#pragma unroll
    for (int i = 0; i < 4; ++i) {
      int p = (i * 4 + w) * 1024 + l * 16;
      int row = p >> 7, ch = ((p >> 4) & 7) ^ (row & 7);
      load_lds16(Bw + (size_t)(n0 + row) * K + kt * 64 + ch * 8,
                 (char*)sB + (i * 4 + w) * 1024);
    }
    __syncthreads();
#pragma unroll
    for (int ks = 0; ks < 2; ++ks) {
      bf16x8 af[MBF], bfr[4];
#pragma unroll
      for (int mb = 0; mb < MBF; ++mb)
        af[mb] = frag128(sA, wr * (BM / 2) + mb * 16 + lr, lq + 4 * ks);
#pragma unroll
      for (int nb = 0; nb < 4; ++nb)
        bfr[nb] = frag128(sB, wc * 64 + nb * 16 + lr, lq + 4 * ks);
#pragma unroll
      for (int mb = 0; mb < MBF; ++mb)
#pragma unroll
        for (int nb = 0; nb < 4; ++nb)
          acc[mb][nb] = __builtin_amdgcn_mfma_f32_16x16x32_bf16(
              af[mb], bfr[nb], acc[mb][nb], 0, 0, 0);
    }
    __syncthreads();
  }

  // epilogue. C/D layout: col = lane&15, row = (lane>>4)*4 + reg  [m89/m91].
#pragma unroll
  for (int nb = 0; nb < 4; ++nb) {
    const int n = n0 + wc * 64 + nb * 16 + lr;
    if constexpr (MODE == 0) {
      const int qkv = n >> 10, c = n & 1023;
      const float* bp = (qkv == 0) ? bias0 : ((qkv == 1) ? bias1 : bias2);
      u16* dp = (qkv == 0) ? o_q : ((qkv == 1) ? o_k : o_v);
      const float bv = bp[c];
      const int h = c >> 6, d = c & 63;
#pragma unroll
      for (int mb = 0; mb < MBF; ++mb)
#pragma unroll
        for (int r = 0; r < 4; ++r) {
          int m = m0 + wr * (BM / 2) + mb * 16 + lq * 4 + r;
          int b = m >> 11, s = m & 2047;
          float v = acc[mb][nb][r] + bv;
          if (qkv == 0) v *= 0.125f;  // fold 1/sqrt(64) into Q
          dp[((size_t)(b * 16 + h) * 2048 + s) * 64 + d] = f2bf(v);
        }
    } else {
      const float bv = bias0[n];
#pragma unroll
      for (int mb = 0; mb < MBF; ++mb)
#pragma unroll
        for (int r = 0; r < 4; ++r) {
          int m = m0 + wr * (BM / 2) + mb * 16 + lq * 4 + r;
          o_f[(size_t)m * 1024 + n] = acc[mb][nb][r] + bv;
        }
    }
  }
}

// ---------------------------------------------------------------- V transpose
// v16 [bh][s][64] -> vt16 [bh][64][s]  (so PV B-operand is contiguous in k)
__global__ __launch_bounds__(256) void transpose_v64(
    const u16* __restrict__ v16, u16* __restrict__ vt16) {
  __shared__ u16 t[64][72];
  const int st = blockIdx.x, bh = blockIdx.y;
  const u16* src = v16 + ((size_t)bh * 2048 + st * 64) * 64;
  u16* dst = vt16 + (size_t)bh * 64 * 2048 + st * 64;
  const int tid = threadIdx.x;
#pragma unroll
  for (int p = 0; p < 2; ++p) {
    int lin = p * 2048 + tid * 8;
    int r = lin >> 6, c = lin & 63;
    u16x8 v = *(const u16x8*)(src + (size_t)r * 64 + c);
#pragma unroll
    for (int j = 0; j < 8; ++j) t[c + j][r] = v[j];
  }
  __syncthreads();
#pragma unroll
  for (int p = 0; p < 2; ++p) {
    int lin = p * 2048 + tid * 8;
    int r = lin >> 6, c = lin & 63;
    u16x8 v;
#pragma unroll
    for (int j = 0; j < 8; ++j) v[j] = t[r][c + j];
    *(u16x8*)(dst + (size_t)r * 2048 + c) = v;
  }
}

// ---------------------------------------------------------------- attention
// grid (16 q-tiles, 32 bh). 4 waves x 32 q-rows, K/V tiles of 128.
// Q pre-scaled by 1/8. Online softmax; P goes through per-wave LDS to
// convert D-layout -> A-layout for the PV MFMA.
__global__ __launch_bounds__(256) void attn_fwd(
    const u16* __restrict__ q16, const u16* __restrict__ k16,
    const u16* __restrict__ vt16, u16* __restrict__ att16) {
  __shared__ u16 sQ[128 * 64];
  __shared__ u16 sK[128 * 64];
  __shared__ u16 sV[64 * 128];
  __shared__ u16 sP[4][32 * 128];
  const int tid = threadIdx.x, l = tid & 63, w = tid >> 6;
  const int lr = l & 15, lq = l >> 4;
  const int qt = blockIdx.x, bh = blockIdx.y;
  const int b = bh >> 4, h = bh & 15;
  const char* qg = (const char*)(q16 + ((size_t)bh * 2048 + qt * 128) * 64);
  const char* kg = (const char*)(k16 + (size_t)bh * 2048 * 64);
  const char* vg = (const char*)(vt16 + (size_t)bh * 64 * 2048);

  // stage Q once (swizzled via pre-swizzled source)
#pragma unroll
  for (int i = 0; i < 4; ++i) {
    int p = (i * 4 + w) * 1024 + l * 16;
    int row = p >> 7, ch = ((p >> 4) & 7) ^ (row & 7);
    load_lds16(qg + (size_t)row * 128 + ch * 16, (char*)sQ + (i * 4 + w) * 1024);
  }

  f32x4 o[2][4];
#pragma unroll
  for (int mb = 0; mb < 2; ++mb)
#pragma unroll
    for (int db = 0; db < 4; ++db) o[mb][db] = f32x4{0.f, 0.f, 0.f, 0.f};
  float m_run[8], l_run[8];
#pragma unroll
  for (int i = 0; i < 8; ++i) { m_run[i] = -1e30f; l_run[i] = 0.f; }

  for (int kt = 0; kt < 16; ++kt) {
    // stage K tile [128][64] and V^T tile [64][128]
#pragma unroll
    for (int i = 0; i < 4; ++i) {
      int p = (i * 4 + w) * 1024 + l * 16;
      int row = p >> 7, ch = ((p >> 4) & 7) ^ (row & 7);
      load_lds16(kg + (size_t)kt * 16384 + (size_t)row * 128 + ch * 16,
                 (char*)sK + (i * 4 + w) * 1024);
    }
#pragma unroll
    for (int i = 0; i < 4; ++i) {
      int p = (i * 4 + w) * 1024 + l * 16;
      int row = p >> 8, ch = ((p >> 4) & 15) ^ (row & 7);
      load_lds16(vg + (size_t)row * 4096 + kt * 256 + ch * 16,
                 (char*)sV + (i * 4 + w) * 1024);
    }
    __syncthreads();  // drains vmcnt(0) before anyone reads LDS

    // S = Q K^T  (per wave: 32 q-rows x 128 k-cols)
    f32x4 s[2][8];
#pragma unroll
    for (int mb = 0; mb < 2; ++mb)
#pragma unroll
      for (int nb = 0; nb < 8; ++nb) s[mb][nb] = f32x4{0.f, 0.f, 0.f, 0.f};
#pragma unroll
    for (int ks = 0; ks < 2; ++ks) {
      bf16x8 aq[2], bk[8];
#pragma unroll
      for (int mb = 0; mb < 2; ++mb)
        aq[mb] = frag128(sQ, w * 32 + mb * 16 + lr, lq + 4 * ks);
#pragma unroll
      for (int nb = 0; nb < 8; ++nb)
        bk[nb] = frag128(sK, nb * 16 + lr, lq + 4 * ks);
#pragma unroll
      for (int mb = 0; mb < 2; ++mb)
#pragma unroll
        for (int nb = 0; nb < 8; ++nb)
          s[mb][nb] = __builtin_amdgcn_mfma_f32_16x16x32_bf16(
              aq[mb], bk[nb], s[mb][nb], 0, 0, 0);
    }

    // online softmax: rows live on 16-lane groups (D-layout)
#pragma unroll
    for (int mb = 0; mb < 2; ++mb)
#pragma unroll
      for (int r = 0; r < 4; ++r) {
        float mx = -1e30f;
#pragma unroll
        for (int nb = 0; nb < 8; ++nb) mx = fmaxf(mx, s[mb][nb][r]);
#pragma unroll
        for (int off = 1; off < 16; off <<= 1)
          mx = fmaxf(mx, __shfl_xor(mx, off, 64));
        const int idx = mb * 4 + r;
        const float mnew = fmaxf(m_run[idx], mx);
        const float alpha = __expf(m_run[idx] - mnew);
        m_run[idx] = mnew;
        float rs = 0.f;
#pragma unroll
        for (int nb = 0; nb < 8; ++nb) {
          float p_ = __expf(s[mb][nb][r] - mnew);
          s[mb][nb][r] = p_;
          rs += p_;
        }
#pragma unroll
        for (int off = 1; off < 16; off <<= 1) rs += __shfl_xor(rs, off, 64);
        l_run[idx] = l_run[idx] * alpha + rs;
#pragma unroll
        for (int db = 0; db < 4; ++db) o[mb][db][r] *= alpha;
      }

    // P (D-layout) -> per-wave LDS (swizzled [32][128] bf16) -> A-layout
#pragma unroll
    for (int mb = 0; mb < 2; ++mb)
#pragma unroll
      for (int nb = 0; nb < 8; ++nb)
#pragma unroll
        for (int r = 0; r < 4; ++r) {
          int q_ = mb * 16 + lq * 4 + r;
          int kcol = nb * 16 + lr;
          int byte = q_ * 256 + ((kcol * 2) ^ ((q_ & 7) << 4));
          *(u16*)((char*)sP[w] + byte) = f2bf(s[mb][nb][r]);
        }

    // O += P V   (compiler inserts lgkmcnt between sP write and read)
#pragma unroll
    for (int kss = 0; kss < 4; ++kss) {
      bf16x8 ap[2], bv[4];
#pragma unroll
      for (int mb = 0; mb < 2; ++mb)
        ap[mb] = frag256(&sP[w][0], mb * 16 + lr, kss * 4 + lq);
#pragma unroll
      for (int db = 0; db < 4; ++db)
        bv[db] = frag256(sV, db * 16 + lr, kss * 4 + lq);
#pragma unroll
      for (int mb = 0; mb < 2; ++mb)
#pragma unroll
        for (int db = 0; db < 4; ++db)
          o[mb][db] = __builtin_amdgcn_mfma_f32_16x16x32_bf16(
              ap[mb], bv[db], o[mb][db], 0, 0, 0);
    }
    __syncthreads();  // before next iter overwrites sK/sV
  }

  // epilogue: O /= l, write bf16 [b][s][h*64+d]
#pragma unroll
  for (int mb = 0; mb < 2; ++mb)
#pragma unroll
    for (int db = 0; db < 4; ++db)
#pragma unroll
      for (int r = 0; r < 4; ++r) {
        float v = o[mb][db][r] / l_run[mb * 4 + r];
        int qg_ = qt * 128 + w * 32 + mb * 16 + lq * 4 + r;
        int col = h * 64 + db * 16 + lr;
        att16[((size_t)(b * 2048 + qg_)) * 1024 + col] = f2bf(v);
      }
}

// ---------------------------------------------------------------- launch
extern "C" void kernel_launch(void* const* d_in, const int* in_sizes, int n_in,
                              void* d_out, int out_size, void* d_ws, size_t ws_size,
                              hipStream_t stream) {
  const float* x  = (const float*)d_in[0];
  const float* Wq = (const float*)d_in[1];
  const float* bq = (const float*)d_in[2];
  const float* Wk = (const float*)d_in[3];
  const float* bk = (const float*)d_in[4];
  const float* Wv = (const float*)d_in[5];
  const float* bv = (const float*)d_in[6];
  const float* Wo = (const float*)d_in[7];
  const float* bo = (const float*)d_in[8];
  float* out = (float*)d_out;

  char* ws = (char*)d_ws;
  const size_t MB = 1024 * 1024;
  if (ws_size < 40 * MB) return;  // need 40 MiB scratch
  u16* x16 = (u16*)(ws);              // 8 MiB; reused as vt16 after QKV GEMM
  u16* w16 = (u16*)(ws + 8 * MB);     // 8 MiB: Wq,Wk,Wv,Wo bf16
  u16* q16 = (u16*)(ws + 16 * MB);    // 8 MiB [bh][s][64], pre-scaled by 1/8
  u16* k16 = (u16*)(ws + 24 * MB);    // 8 MiB [bh][s][64]
  u16* v16 = (u16*)(ws + 32 * MB);    // 8 MiB; reused as att16 after transpose
  u16* vt16 = x16;
  u16* att16 = v16;

  // fp32 -> bf16
  cvt_f32_to_bf16<<<4096, 256, 0, stream>>>(x, x16, 1048576);
  cvt_f32_to_bf16<<<1024, 256, 0, stream>>>(Wq, w16, 262144);
  cvt_f32_to_bf16<<<1024, 256, 0, stream>>>(Wk, w16 + 1048576, 262144);
  cvt_f32_to_bf16<<<1024, 256, 0, stream>>>(Wv, w16 + 2097152, 262144);
  cvt_f32_to_bf16<<<1024, 256, 0, stream>>>(Wo, w16 + 3145728, 262144);

  // fused QKV projection: [4096,1024] @ [3072,1024]^T
  gemm_bf16<128, 0><<<dim3(24, 32), 256, 0, stream>>>(
      x16, w16, bq, bk, bv, q16, k16, v16, nullptr, 1024);

  // V -> V^T per (b,h)
  transpose_v64<<<dim3(32, 32), 256, 0, stream>>>(v16, vt16);

  // flash attention
  attn_fwd<<<dim3(16, 32), 256, 0, stream>>>(q16, k16, vt16, att16);

  // out projection: [4096,1024] @ [1024,1024]^T + bo -> fp32
  gemm_bf16<64, 1><<<dim3(8, 64), 256, 0, stream>>>(
      att16, w16 + 3145728, bo, nullptr, nullptr, nullptr, nullptr, nullptr,
      out, 1024);
}